// Round 1
// baseline (976.078 us; speedup 1.0000x reference)
//
#include <hip/hip_runtime.h>
#include <math.h>

#define S_DIM 8
#define N_DIM 2048
#define K_DIM 64

#define TPB 256
#define APB 4     // atoms per block

#define ST_S 36   // s_tilde row stride (floats), 16B-aligned rows, breaks bank conflicts
#define ST_H 68   // h1 row stride (floats), 16B-aligned rows

// ---------------------------------------------------------------------------
// Precompute td table: td_tab[pair(2x2)][32] ; [0..30] = f-MLP(emb(c,t)+emb(t,c)), [31]=pad
// ---------------------------------------------------------------------------
__global__ void td_precompute(const float* __restrict__ ew0, const float* __restrict__ eb0,
                              const float* __restrict__ ew1, const float* __restrict__ eb1,
                              const float* __restrict__ fw0, const float* __restrict__ fb0,
                              const float* __restrict__ fw1, const float* __restrict__ fb1,
                              float* __restrict__ td_tab) {
    int p = threadIdx.x;
    if (p >= 4) return;
    float c = (float)(p >> 1);
    float t = (float)(p & 1);
    float tv[32];
#pragma unroll
    for (int j = 0; j < 32; j++) tv[j] = 0.f;
    for (int ord = 0; ord < 2; ord++) {
        float x0 = ord ? t : c;
        float x1 = ord ? c : t;
        float h[16];
#pragma unroll
        for (int j = 0; j < 16; j++)
            h[j] = fmaxf(x0 * ew0[j] + x1 * ew0[16 + j] + eb0[j], 0.f);
#pragma unroll
        for (int j = 0; j < 32; j++) {
            float v = eb1[j];
#pragma unroll
            for (int i = 0; i < 16; i++) v += h[i] * ew1[i * 32 + j];
            tv[j] += fmaxf(v, 0.f);
        }
    }
    float f1[32];
#pragma unroll
    for (int j = 0; j < 32; j++) {
        float v = fb0[j];
#pragma unroll
        for (int i = 0; i < 32; i++) v += tv[i] * fw0[i * 32 + j];
        f1[j] = fmaxf(v, 0.f);
    }
#pragma unroll
    for (int j = 0; j < 31; j++) {
        float v = fb1[j];
#pragma unroll
        for (int i = 0; i < 32; i++) v += f1[i] * fw1[i * 31 + j];
        td_tab[p * 32 + j] = fmaxf(v, 0.f);
    }
    td_tab[p * 32 + 31] = 0.f;
}

// ---------------------------------------------------------------------------
// Main fused kernel: per atom -> s_tilde/r_tilde -> G-MLP -> A = G^T r_tilde
// -> D = A @ A[:16]^T
// ---------------------------------------------------------------------------
__global__ __launch_bounds__(TPB, 2) void descr_main(
    const float* __restrict__ inputs,       // S*N*3
    const int*   __restrict__ input_types,  // S*N
    const int*   __restrict__ neigh_list,   // S*N*K
    const float* __restrict__ length,       // 3
    const float* __restrict__ gw0,          // 32*64 (streamed from global/L1)
    const float* __restrict__ gb0,          // 64
    const float* __restrict__ gw1,          // 64*128
    const float* __restrict__ gb1,          // 128
    const float* __restrict__ td_tab,       // 4*32
    float* __restrict__ out)                // S*N*128*16
{
    __shared__ __align__(16) float s_gw1[64 * 128];   // 32 KB
    __shared__ __align__(16) float s_st[64 * ST_S];   // 9 KB
    __shared__ __align__(16) float s_h1[64 * ST_H];   // 17 KB
    __shared__ __align__(16) float s_rt[64 * 4];      // 1 KB
    __shared__ __align__(16) float s_A[128 * 4];      // 2 KB
    __shared__ __align__(16) float s_td[4 * 32];      // 0.5 KB
    __shared__ __align__(16) float s_gb0[64];
    __shared__ __align__(16) float s_gb1[128];

    const int tid = threadIdx.x;

    for (int i = tid; i < 64 * 128; i += TPB) s_gw1[i] = gw1[i];
    if (tid < 64)  s_gb0[tid] = gb0[tid];
    if (tid < 128) s_gb1[tid] = gb1[tid];
    if (tid < 128) s_td[tid]  = td_tab[tid];

    const float Lx = length[0], Ly = length[1], Lz = length[2];

    for (int aa = 0; aa < APB; aa++) {
        const int atom = blockIdx.x * APB + aa;
        const int s_idx = atom >> 11;  // atom / N_DIM

        __syncthreads();  // covers weight preload (1st iter) and s_A reuse (later iters)

        if (tid < 128) ((float4*)s_A)[tid] = make_float4(0.f, 0.f, 0.f, 0.f);

        if (tid < 64) {
            const int k = tid;
            const int nb = neigh_list[atom * K_DIM + k];
            const bool msk = nb < 0;
            const int idx = msk ? 0 : nb;
            const float cx = inputs[atom * 3 + 0];
            const float cy = inputs[atom * 3 + 1];
            const float cz = inputs[atom * 3 + 2];
            const int nbase = (s_idx * N_DIM + idx) * 3;
            float dx = inputs[nbase + 0] - cx;
            float dy = inputs[nbase + 1] - cy;
            float dz = inputs[nbase + 2] - cz;
            dx -= Lx * rintf(dx / Lx);
            dy -= Ly * rintf(dy / Ly);
            dz -= Lz * rintf(dz / Lz);
            const float rsq = dx * dx + dy * dy + dz * dz;
            const float r = sqrtf(rsq > 0.f ? rsq : 1.f);
            const float inv = 1.f / r;
            float sw;
            if (r < 6.f) sw = inv;
            else if (r < 12.f) {
                const float u = (r - 6.f) * (1.f / 6.f);
                sw = inv * (0.5f * cosf(3.14159265358979323846f * u) + 0.5f);
            } else sw = 0.f;
            const bool valid = (!msk) && (rsq > 0.f);
            const float sij = valid ? sw : 0.f;
            const float f = sij * inv;
            s_rt[k * 4 + 0] = sij;
            s_rt[k * 4 + 1] = dx * f;
            s_rt[k * 4 + 2] = dy * f;
            s_rt[k * 4 + 3] = dz * f;
            const int ct = input_types[atom];
            const int nt = input_types[s_idx * N_DIM + idx];
            const float* row = &s_td[(ct * 2 + nt) * 32];
            const float zm = msk ? 0.f : 1.f;
#pragma unroll
            for (int i = 0; i < 31; i++) s_st[k * ST_S + i] = zm * row[i];
            s_st[k * ST_S + 31] = sij;
        }
        __syncthreads();

        // ---- Layer 1: h1[k][j] = relu(s_tilde[k] @ gw0 + gb0) + s_tilde[k][j&31]
        {
            const int jt = tid & 15, kt = tid >> 4;
            const int j0 = jt * 4, k0 = kt * 4;
            float acc[4][4] = {};
            const float4* w4 = (const float4*)gw0;
#pragma unroll 8
            for (int i = 0; i < 32; i++) {
                const float4 w = w4[(i * 64 + j0) >> 2];
                const float s0 = s_st[(k0 + 0) * ST_S + i];
                const float s1 = s_st[(k0 + 1) * ST_S + i];
                const float s2 = s_st[(k0 + 2) * ST_S + i];
                const float s3 = s_st[(k0 + 3) * ST_S + i];
                acc[0][0] += s0 * w.x; acc[0][1] += s0 * w.y; acc[0][2] += s0 * w.z; acc[0][3] += s0 * w.w;
                acc[1][0] += s1 * w.x; acc[1][1] += s1 * w.y; acc[1][2] += s1 * w.z; acc[1][3] += s1 * w.w;
                acc[2][0] += s2 * w.x; acc[2][1] += s2 * w.y; acc[2][2] += s2 * w.z; acc[2][3] += s2 * w.w;
                acc[3][0] += s3 * w.x; acc[3][1] += s3 * w.y; acc[3][2] += s3 * w.z; acc[3][3] += s3 * w.w;
            }
            const float4 b = *(const float4*)&s_gb0[j0];
            const int jm = j0 & 31;
#pragma unroll
            for (int kk = 0; kk < 4; kk++) {
                const float4 res = *(const float4*)&s_st[(k0 + kk) * ST_S + jm];
                float4 h;
                h.x = fmaxf(acc[kk][0] + b.x, 0.f) + res.x;
                h.y = fmaxf(acc[kk][1] + b.y, 0.f) + res.y;
                h.z = fmaxf(acc[kk][2] + b.z, 0.f) + res.z;
                h.w = fmaxf(acc[kk][3] + b.w, 0.f) + res.w;
                *(float4*)&s_h1[(k0 + kk) * ST_H + j0] = h;
            }
        }
        __syncthreads();

        // ---- Layer 2 + A accumulation: g[k][e] = relu(h1[k] @ gw1 + gb1) + h1[k][e&63]
        //      A[e][d] += g[k][e] * r_tilde[k][d]
        {
            const int e4 = tid & 31, kq = tid >> 5;
            const int e0 = e4 * 4, k0 = kq * 8;
            float acc[8][4];
            const float4 b = *(const float4*)&s_gb1[e0];
#pragma unroll
            for (int kk = 0; kk < 8; kk++) { acc[kk][0] = b.x; acc[kk][1] = b.y; acc[kk][2] = b.z; acc[kk][3] = b.w; }
#pragma unroll 2
            for (int j4 = 0; j4 < 16; j4++) {
                const float4 w0 = *(const float4*)&s_gw1[(j4 * 4 + 0) * 128 + e0];
                const float4 w1 = *(const float4*)&s_gw1[(j4 * 4 + 1) * 128 + e0];
                const float4 w2 = *(const float4*)&s_gw1[(j4 * 4 + 2) * 128 + e0];
                const float4 w3 = *(const float4*)&s_gw1[(j4 * 4 + 3) * 128 + e0];
#pragma unroll
                for (int kk = 0; kk < 8; kk++) {
                    const float4 h = *(const float4*)&s_h1[(k0 + kk) * ST_H + j4 * 4];
                    acc[kk][0] += h.x * w0.x + h.y * w1.x + h.z * w2.x + h.w * w3.x;
                    acc[kk][1] += h.x * w0.y + h.y * w1.y + h.z * w2.y + h.w * w3.y;
                    acc[kk][2] += h.x * w0.z + h.y * w1.z + h.z * w2.z + h.w * w3.z;
                    acc[kk][3] += h.x * w0.w + h.y * w1.w + h.z * w2.w + h.w * w3.w;
                }
            }
            float Ap[4][4] = {};
            const int em = e0 & 63;
#pragma unroll
            for (int kk = 0; kk < 8; kk++) {
                const int k = k0 + kk;
                const float4 res = *(const float4*)&s_h1[k * ST_H + em];
                const float4 rt  = *(const float4*)&s_rt[k * 4];
                const float g0 = fmaxf(acc[kk][0], 0.f) + res.x;
                const float g1 = fmaxf(acc[kk][1], 0.f) + res.y;
                const float g2 = fmaxf(acc[kk][2], 0.f) + res.z;
                const float g3 = fmaxf(acc[kk][3], 0.f) + res.w;
                Ap[0][0] += g0 * rt.x; Ap[0][1] += g0 * rt.y; Ap[0][2] += g0 * rt.z; Ap[0][3] += g0 * rt.w;
                Ap[1][0] += g1 * rt.x; Ap[1][1] += g1 * rt.y; Ap[1][2] += g1 * rt.z; Ap[1][3] += g1 * rt.w;
                Ap[2][0] += g2 * rt.x; Ap[2][1] += g2 * rt.y; Ap[2][2] += g2 * rt.z; Ap[2][3] += g2 * rt.w;
                Ap[3][0] += g3 * rt.x; Ap[3][1] += g3 * rt.y; Ap[3][2] += g3 * rt.z; Ap[3][3] += g3 * rt.w;
            }
#pragma unroll
            for (int ee = 0; ee < 4; ee++)
#pragma unroll
                for (int d = 0; d < 4; d++)
                    atomicAdd(&s_A[(e0 + ee) * 4 + d], Ap[ee][d]);
        }
        __syncthreads();

        // ---- D[e][m] = sum_d A[e][d] * A[m][d],  m in [0,16)
        {
            const int e = tid >> 1, mh = (tid & 1) * 8;
            const float4 Ae = *(const float4*)&s_A[e * 4];
            float res[8];
#pragma unroll
            for (int mm = 0; mm < 8; mm++) {
                const float4 Am = *(const float4*)&s_A[(mh + mm) * 4];
                res[mm] = Ae.x * Am.x + Ae.y * Am.y + Ae.z * Am.z + Ae.w * Am.w;
            }
            const size_t ob = ((size_t)atom * 128 + e) * 16 + mh;
            float4 o0, o1;
            o0.x = res[0]; o0.y = res[1]; o0.z = res[2]; o0.w = res[3];
            o1.x = res[4]; o1.y = res[5]; o1.z = res[6]; o1.w = res[7];
            *(float4*)&out[ob]     = o0;
            *(float4*)&out[ob + 4] = o1;
        }
    }
}

extern "C" void kernel_launch(void* const* d_in, const int* in_sizes, int n_in,
                              void* d_out, int out_size, void* d_ws, size_t ws_size,
                              hipStream_t stream) {
    (void)in_sizes; (void)n_in; (void)out_size; (void)ws_size;
    const float* inputs      = (const float*)d_in[0];
    const int*   input_types = (const int*)d_in[1];
    const int*   neigh_list  = (const int*)d_in[2];
    const float* length      = (const float*)d_in[3];
    const float* ew0 = (const float*)d_in[4];
    const float* eb0 = (const float*)d_in[5];
    const float* ew1 = (const float*)d_in[6];
    const float* eb1 = (const float*)d_in[7];
    const float* fw0 = (const float*)d_in[8];
    const float* fb0 = (const float*)d_in[9];
    const float* fw1 = (const float*)d_in[10];
    const float* fb1 = (const float*)d_in[11];
    const float* gw0 = (const float*)d_in[12];
    const float* gb0 = (const float*)d_in[13];
    const float* gw1 = (const float*)d_in[14];
    const float* gb1 = (const float*)d_in[15];
    float* out    = (float*)d_out;
    float* td_tab = (float*)d_ws;   // 128 floats

    hipLaunchKernelGGL(td_precompute, dim3(1), dim3(64), 0, stream,
                       ew0, eb0, ew1, eb1, fw0, fb0, fw1, fb1, td_tab);

    const int nblocks = (S_DIM * N_DIM) / APB;
    hipLaunchKernelGGL(descr_main, dim3(nblocks), dim3(TPB), 0, stream,
                       inputs, input_types, neigh_list, length,
                       gw0, gb0, gw1, gb1, td_tab, out);
}

// Round 2
// 330.262 us; speedup vs baseline: 2.9555x; 2.9555x over previous
//
#include <hip/hip_runtime.h>
#include <math.h>

#define S_DIM 8
#define N_DIM 2048
#define K_DIM 64
#define APW 8          // atoms per wave (= per 64-thread block)
#define ST_ST 40       // s_tilde row stride, bf16 units (80 B, 16B-aligned, conflict-safe)
#define ST_H1 72       // h1 row stride, bf16 units (144 B, 16B-aligned, conflict-safe)

typedef __attribute__((ext_vector_type(8))) short bf16x8;
typedef __attribute__((ext_vector_type(4))) float f32x4;

__device__ __forceinline__ unsigned short f2bf(float x) {
    union { float f; unsigned u; } v; v.f = x;
    unsigned r = (v.u + 0x7FFFu + ((v.u >> 16) & 1u)) >> 16;
    return (unsigned short)r;
}
__device__ __forceinline__ float bf2f(unsigned short h) {
    union { unsigned u; float f; } v; v.u = ((unsigned)h) << 16;
    return v.f;
}
__device__ __forceinline__ f32x4 quad_reduce(f32x4 v) {
    v[0] += __shfl_xor(v[0], 16); v[1] += __shfl_xor(v[1], 16);
    v[2] += __shfl_xor(v[2], 16); v[3] += __shfl_xor(v[3], 16);
    v[0] += __shfl_xor(v[0], 32); v[1] += __shfl_xor(v[1], 32);
    v[2] += __shfl_xor(v[2], 32); v[3] += __shfl_xor(v[3], 32);
    return v;
}

// ---------------------------------------------------------------------------
// Prep: td table (4 type-pairs x 32) + bf16-transposed weights into ws.
// W0T[j][i] (64x32), W1T[e][j] (128x64): B/A-fragment reads become contiguous.
// ---------------------------------------------------------------------------
__global__ void prep_kernel(const float* __restrict__ ew0, const float* __restrict__ eb0,
                            const float* __restrict__ ew1, const float* __restrict__ eb1,
                            const float* __restrict__ fw0, const float* __restrict__ fb0,
                            const float* __restrict__ fw1, const float* __restrict__ fb1,
                            const float* __restrict__ gw0, const float* __restrict__ gw1,
                            float* __restrict__ td_tab,
                            unsigned short* __restrict__ w0t, unsigned short* __restrict__ w1t) {
    const int tid = threadIdx.x;
    if (tid < 4) {
        const int p = tid;
        const float c = (float)(p >> 1), t = (float)(p & 1);
        float tv[32];
#pragma unroll
        for (int j = 0; j < 32; j++) tv[j] = 0.f;
        for (int ord = 0; ord < 2; ord++) {
            const float x0 = ord ? t : c;
            const float x1 = ord ? c : t;
            float h[16];
#pragma unroll
            for (int j = 0; j < 16; j++)
                h[j] = fmaxf(x0 * ew0[j] + x1 * ew0[16 + j] + eb0[j], 0.f);
#pragma unroll
            for (int j = 0; j < 32; j++) {
                float v = eb1[j];
#pragma unroll
                for (int i = 0; i < 16; i++) v += h[i] * ew1[i * 32 + j];
                tv[j] += fmaxf(v, 0.f);
            }
        }
        float f1[32];
#pragma unroll
        for (int j = 0; j < 32; j++) {
            float v = fb0[j];
#pragma unroll
            for (int i = 0; i < 32; i++) v += tv[i] * fw0[i * 32 + j];
            f1[j] = fmaxf(v, 0.f);
        }
#pragma unroll
        for (int j = 0; j < 31; j++) {
            float v = fb1[j];
#pragma unroll
            for (int i = 0; i < 32; i++) v += f1[i] * fw1[i * 31 + j];
            td_tab[p * 32 + j] = fmaxf(v, 0.f);
        }
        td_tab[p * 32 + 31] = 0.f;
    }
    for (int idx = tid; idx < 2048; idx += 256) {   // W0T[j*32+i] = gw0[i][j]
        const int j = idx >> 5, i = idx & 31;
        w0t[idx] = f2bf(gw0[i * 64 + j]);
    }
    for (int idx = tid; idx < 8192; idx += 256) {   // W1T[e*64+j] = gw1[j][e]
        const int e = idx >> 6, j = idx & 63;
        w1t[idx] = f2bf(gw1[j * 128 + e]);
    }
}

// ---------------------------------------------------------------------------
// Main: one wave per block, APW atoms per wave. Per atom:
// geometry -> st(bf16,LDS) -> L1 MFMA(+bias,relu,+st residual) -> h1(bf16,LDS)
//   + B[j][d] = sum_k h1[k][j] * rt[k][d]            (G residual, pushed down)
// L2 MFMA -> relu part folded directly into A[e][d] (+= B[e&63])
// D[e][m] = sum_d A[e][d]*A[m][d], coalesced float4 stores.
// ---------------------------------------------------------------------------
__global__ __launch_bounds__(64, 2) void descr_mfma(
    const float* __restrict__ inputs, const int* __restrict__ input_types,
    const int* __restrict__ neigh_list, const float* __restrict__ length,
    const float* __restrict__ gb0, const float* __restrict__ gb1,
    const float* __restrict__ td_tab, const unsigned short* __restrict__ w0t,
    const unsigned short* __restrict__ w1t, float* __restrict__ out)
{
    __shared__ __align__(16) unsigned short s_st[64 * ST_ST];  // 5 KB
    __shared__ __align__(16) unsigned short s_h1[64 * ST_H1];  // 9 KB
    __shared__ __align__(16) float s_rt[64 * 4];               // 1 KB
    __shared__ __align__(16) float s_A[128 * 4];               // 2 KB
    __shared__ __align__(16) float s_B[64 * 4];                // 1 KB

    const int lane = threadIdx.x;
    const int l15 = lane & 15;
    const int q = lane >> 4;

    // Weight fragments, resident in registers for the whole wave lifetime.
    // B-frag layout (16x16x32): lane holds B[k = q*8 + jj][n = l15 (+16*tile)]
    bf16x8 w0f[4];
#pragma unroll
    for (int nt = 0; nt < 4; nt++)
        w0f[nt] = *(const bf16x8*)&w0t[(nt * 16 + l15) * 32 + q * 8];
    bf16x8 w1f[8][2];
#pragma unroll
    for (int et = 0; et < 8; et++) {
        w1f[et][0] = *(const bf16x8*)&w1t[(et * 16 + l15) * 64 + q * 8];
        w1f[et][1] = *(const bf16x8*)&w1t[(et * 16 + l15) * 64 + 32 + q * 8];
    }
    float b0f[4], b1f[8];
#pragma unroll
    for (int jt = 0; jt < 4; jt++) b0f[jt] = gb0[jt * 16 + l15];
#pragma unroll
    for (int et = 0; et < 8; et++) b1f[et] = gb1[et * 16 + l15];
    const float Lx = length[0], Ly = length[1], Lz = length[2];

    for (int aa = 0; aa < APW; aa++) {
        const int atom = blockIdx.x * APW + aa;
        const int sidx = atom >> 11;

        // ---- geometry: lane = neighbor k
        {
            const int nb = neigh_list[atom * K_DIM + lane];
            const bool msk = nb < 0;
            const int idx = msk ? 0 : nb;
            const float cx = inputs[atom * 3 + 0];
            const float cy = inputs[atom * 3 + 1];
            const float cz = inputs[atom * 3 + 2];
            const int nbase = (sidx * N_DIM + idx) * 3;
            float dx = inputs[nbase + 0] - cx;
            float dy = inputs[nbase + 1] - cy;
            float dz = inputs[nbase + 2] - cz;
            dx -= Lx * rintf(dx / Lx);
            dy -= Ly * rintf(dy / Ly);
            dz -= Lz * rintf(dz / Lz);
            const float rsq = dx * dx + dy * dy + dz * dz;
            const float r = sqrtf(rsq > 0.f ? rsq : 1.f);
            const float inv = 1.f / r;
            float sw;
            if (r < 6.f) sw = inv;
            else if (r < 12.f) {
                const float u = (r - 6.f) * (1.f / 6.f);
                sw = inv * (0.5f * __cosf(3.14159265358979323846f * u) + 0.5f);
            } else sw = 0.f;
            const bool valid = (!msk) && (rsq > 0.f);
            const float sij = valid ? sw : 0.f;
            const float f = sij * inv;
            *(float4*)&s_rt[lane * 4] = make_float4(sij, dx * f, dy * f, dz * f);

            const int ct = input_types[atom];
            const int ntp = input_types[sidx * N_DIM + idx];
            const float* tdr = &td_tab[(ct * 2 + ntp) * 32];
            const float zm = msk ? 0.f : 1.f;
            unsigned* strow = (unsigned*)&s_st[lane * ST_ST];
#pragma unroll
            for (int i = 0; i < 16; i++) {
                const float a = tdr[2 * i] * zm;
                const float b = (i == 15) ? sij : tdr[2 * i + 1] * zm;
                strow[i] = (unsigned)f2bf(a) | ((unsigned)f2bf(b) << 16);
            }
        }
        __syncthreads();

        // ---- L1 (M=k64, N=j64, K=i32) + B-term accumulation
        f32x4 Bp[4] = {{0.f,0.f,0.f,0.f},{0.f,0.f,0.f,0.f},{0.f,0.f,0.f,0.f},{0.f,0.f,0.f,0.f}};
#pragma unroll
        for (int mt = 0; mt < 4; mt++) {
            const bf16x8 afr = *(const bf16x8*)&s_st[(mt * 16 + l15) * ST_ST + q * 8];
            f32x4 c1[4];
#pragma unroll
            for (int jt = 0; jt < 4; jt++) {
                f32x4 z = {0.f, 0.f, 0.f, 0.f};
                c1[jt] = __builtin_amdgcn_mfma_f32_16x16x32_bf16(afr, w0f[jt], z, 0, 0, 0);
            }
            f32x4 rtr[4];
#pragma unroll
            for (int reg = 0; reg < 4; reg++)
                rtr[reg] = *(const f32x4*)&s_rt[(mt * 16 + q * 4 + reg) * 4];
#pragma unroll
            for (int jt = 0; jt < 4; jt++) {
                const int jcol = (jt & 1) * 16 + l15;
#pragma unroll
                for (int reg = 0; reg < 4; reg++) {
                    const int k = mt * 16 + q * 4 + reg;
                    const float h = fmaxf(c1[jt][reg] + b0f[jt], 0.f) + bf2f(s_st[k * ST_ST + jcol]);
                    Bp[jt] += h * rtr[reg];
                    s_h1[k * ST_H1 + jt * 16 + l15] = f2bf(h);
                }
            }
        }
#pragma unroll
        for (int jt = 0; jt < 4; jt++) Bp[jt] = quad_reduce(Bp[jt]);
        if (lane < 16) {
#pragma unroll
            for (int jt = 0; jt < 4; jt++)
                *(f32x4*)&s_B[(jt * 16 + lane) * 4] = Bp[jt];
        }
        __syncthreads();

        // ---- L2 (M=k64, N=e128, K=j64) + A accumulation (relu part only)
        f32x4 Ap[8] = {{0.f,0.f,0.f,0.f},{0.f,0.f,0.f,0.f},{0.f,0.f,0.f,0.f},{0.f,0.f,0.f,0.f},
                       {0.f,0.f,0.f,0.f},{0.f,0.f,0.f,0.f},{0.f,0.f,0.f,0.f},{0.f,0.f,0.f,0.f}};
#pragma unroll
        for (int kt = 0; kt < 4; kt++) {
            const bf16x8 a0 = *(const bf16x8*)&s_h1[(kt * 16 + l15) * ST_H1 + q * 8];
            const bf16x8 a1 = *(const bf16x8*)&s_h1[(kt * 16 + l15) * ST_H1 + 32 + q * 8];
            f32x4 rtr[4];
#pragma unroll
            for (int reg = 0; reg < 4; reg++)
                rtr[reg] = *(const f32x4*)&s_rt[(kt * 16 + q * 4 + reg) * 4];
#pragma unroll
            for (int et = 0; et < 8; et++) {
                f32x4 c2 = {0.f, 0.f, 0.f, 0.f};
                c2 = __builtin_amdgcn_mfma_f32_16x16x32_bf16(a0, w1f[et][0], c2, 0, 0, 0);
                c2 = __builtin_amdgcn_mfma_f32_16x16x32_bf16(a1, w1f[et][1], c2, 0, 0, 0);
#pragma unroll
                for (int reg = 0; reg < 4; reg++) {
                    const float g = fmaxf(c2[reg] + b1f[et], 0.f);
                    Ap[et] += g * rtr[reg];
                }
            }
        }
#pragma unroll
        for (int et = 0; et < 8; et++) Ap[et] = quad_reduce(Ap[et]);
        if (lane < 16) {
#pragma unroll
            for (int et = 0; et < 8; et++) {
                const int e = et * 16 + lane;
                const f32x4 bb = *(const f32x4*)&s_B[(e & 63) * 4];
                const f32x4 v = Ap[et] + bb;
                *(f32x4*)&s_A[e * 4] = v;
            }
        }
        __syncthreads();

        // ---- D[e][m] = dot(A[e], A[m]), m<16; coalesced float4 stores
        {
            const int m0 = (lane & 3) * 4;
            const int er = lane >> 2;
            f32x4 Am[4];
#pragma unroll
            for (int t = 0; t < 4; t++) Am[t] = *(const f32x4*)&s_A[(m0 + t) * 4];
            float* op = out + (size_t)atom * 2048;
#pragma unroll
            for (int g = 0; g < 8; g++) {
                const int e = g * 16 + er;
                const f32x4 Ae = *(const f32x4*)&s_A[e * 4];
                f32x4 o;
                o[0] = Ae[0]*Am[0][0] + Ae[1]*Am[0][1] + Ae[2]*Am[0][2] + Ae[3]*Am[0][3];
                o[1] = Ae[0]*Am[1][0] + Ae[1]*Am[1][1] + Ae[2]*Am[1][2] + Ae[3]*Am[1][3];
                o[2] = Ae[0]*Am[2][0] + Ae[1]*Am[2][1] + Ae[2]*Am[2][2] + Ae[3]*Am[2][3];
                o[3] = Ae[0]*Am[3][0] + Ae[1]*Am[3][1] + Ae[2]*Am[3][2] + Ae[3]*Am[3][3];
                *(f32x4*)&op[e * 16 + m0] = o;
            }
        }
        __syncthreads();
    }
}

extern "C" void kernel_launch(void* const* d_in, const int* in_sizes, int n_in,
                              void* d_out, int out_size, void* d_ws, size_t ws_size,
                              hipStream_t stream) {
    (void)in_sizes; (void)n_in; (void)out_size; (void)ws_size;
    const float* inputs      = (const float*)d_in[0];
    const int*   input_types = (const int*)d_in[1];
    const int*   neigh_list  = (const int*)d_in[2];
    const float* length      = (const float*)d_in[3];
    const float* ew0 = (const float*)d_in[4];
    const float* eb0 = (const float*)d_in[5];
    const float* ew1 = (const float*)d_in[6];
    const float* eb1 = (const float*)d_in[7];
    const float* fw0 = (const float*)d_in[8];
    const float* fb0 = (const float*)d_in[9];
    const float* fw1 = (const float*)d_in[10];
    const float* fb1 = (const float*)d_in[11];
    const float* gw0 = (const float*)d_in[12];
    const float* gb0 = (const float*)d_in[13];
    const float* gw1 = (const float*)d_in[14];
    const float* gb1 = (const float*)d_in[15];
    float* out = (float*)d_out;

    float* td_tab = (float*)d_ws;                                    // 128 f32
    unsigned short* w0t = (unsigned short*)((char*)d_ws + 512);      // 2048 bf16
    unsigned short* w1t = (unsigned short*)((char*)d_ws + 512 + 4096); // 8192 bf16

    hipLaunchKernelGGL(prep_kernel, dim3(1), dim3(256), 0, stream,
                       ew0, eb0, ew1, eb1, fw0, fb0, fw1, fb1, gw0, gw1,
                       td_tab, w0t, w1t);

    const int nblocks = (S_DIM * N_DIM) / APW;   // 2048
    hipLaunchKernelGGL(descr_mfma, dim3(nblocks), dim3(64), 0, stream,
                       inputs, input_types, neigh_list, length,
                       gb0, gb1, td_tab, w0t, w1t, out);
}

// Round 3
// 245.200 us; speedup vs baseline: 3.9807x; 1.3469x over previous
//
#include <hip/hip_runtime.h>
#include <math.h>

#define S_DIM 8
#define N_DIM 2048
#define K_DIM 64
#define APW 4          // atoms per wave (= per 64-thread block)
#define ST_ST 40       // s_tilde row stride, bf16 units (80 B, 16B-aligned, conflict-safe)
#define ST_H1 72       // h1 row stride, bf16 units (144 B, 16B-aligned, conflict-safe)

typedef __attribute__((ext_vector_type(8))) short bf16x8;
typedef __attribute__((ext_vector_type(4))) float f32x4;

__device__ __forceinline__ unsigned short f2bf(float x) {
    union { float f; unsigned u; } v; v.f = x;
    unsigned r = (v.u + 0x7FFFu + ((v.u >> 16) & 1u)) >> 16;
    return (unsigned short)r;
}
__device__ __forceinline__ float bf2f(unsigned short h) {
    union { unsigned u; float f; } v; v.u = ((unsigned)h) << 16;
    return v.f;
}
__device__ __forceinline__ f32x4 quad_reduce(f32x4 v) {
    v[0] += __shfl_xor(v[0], 16); v[1] += __shfl_xor(v[1], 16);
    v[2] += __shfl_xor(v[2], 16); v[3] += __shfl_xor(v[3], 16);
    v[0] += __shfl_xor(v[0], 32); v[1] += __shfl_xor(v[1], 32);
    v[2] += __shfl_xor(v[2], 32); v[3] += __shfl_xor(v[3], 32);
    return v;
}

// ---------------------------------------------------------------------------
// Prep: td table (4 type-pairs x 32) + bf16-transposed weights into ws.
// All weights staged into LDS coalesced first; MLP parallelized over
// (pair, unit) so every dot-product is LDS-broadcast reads, no global
// pointer-chase. R2 lesson: the 4-thread global-load version was 103 us
// of serialized L2 latency.
// ---------------------------------------------------------------------------
__global__ __launch_bounds__(256) void prep_kernel(
        const float* __restrict__ ew0, const float* __restrict__ eb0,
        const float* __restrict__ ew1, const float* __restrict__ eb1,
        const float* __restrict__ fw0, const float* __restrict__ fb0,
        const float* __restrict__ fw1, const float* __restrict__ fb1,
        const float* __restrict__ gw0, const float* __restrict__ gw1,
        float* __restrict__ td_tab,
        unsigned short* __restrict__ w0t, unsigned short* __restrict__ w1t) {
    __shared__ float l_ew0[32], l_eb0[16], l_ew1[512], l_eb1[32];
    __shared__ float l_fw0[1024], l_fb0[32], l_fw1[992], l_fb1[31];
    __shared__ float l_h[4][2][16];
    __shared__ float l_tv[4][32];
    __shared__ float l_f1[4][32];

    const int tid = threadIdx.x;
    // ---- stage weights (coalesced)
    if (tid < 32) l_ew0[tid] = ew0[tid];
    if (tid < 16) l_eb0[tid] = eb0[tid];
    for (int i = tid; i < 512; i += 256) l_ew1[i] = ew1[i];
    if (tid < 32) l_eb1[tid] = eb1[tid];
    for (int i = tid; i < 1024; i += 256) l_fw0[i] = fw0[i];
    if (tid < 32) l_fb0[tid] = fb0[tid];
    for (int i = tid; i < 992; i += 256) l_fw1[i] = fw1[i];
    if (tid < 31) l_fb1[tid] = fb1[tid];
    __syncthreads();

    // ---- emb layer 0: h[p][ord][j], 128 threads
    if (tid < 128) {
        const int p = tid >> 5, ord = (tid >> 4) & 1, j = tid & 15;
        const float c = (float)(p >> 1), t = (float)(p & 1);
        const float x0 = ord ? t : c;
        const float x1 = ord ? c : t;
        l_h[p][ord][j] = fmaxf(x0 * l_ew0[j] + x1 * l_ew0[16 + j] + l_eb0[j], 0.f);
    }
    __syncthreads();

    // ---- emb layer 1 summed over orders: tv[p][j], 128 threads
    if (tid < 128) {
        const int p = tid >> 5, j = tid & 31;
        float acc = 0.f;
#pragma unroll
        for (int ord = 0; ord < 2; ord++) {
            float v = l_eb1[j];
#pragma unroll
            for (int i = 0; i < 16; i++) v += l_h[p][ord][i] * l_ew1[i * 32 + j];
            acc += fmaxf(v, 0.f);
        }
        l_tv[p][j] = acc;
    }
    __syncthreads();

    // ---- f layer 0: f1[p][j]
    if (tid < 128) {
        const int p = tid >> 5, j = tid & 31;
        float v = l_fb0[j];
#pragma unroll
        for (int i = 0; i < 32; i++) v += l_tv[p][i] * l_fw0[i * 32 + j];
        l_f1[p][j] = fmaxf(v, 0.f);
    }
    __syncthreads();

    // ---- f layer 1: td_tab[p][j], j<31 (+pad)
    if (tid < 128) {
        const int p = tid >> 5, j = tid & 31;
        if (j < 31) {
            float v = l_fb1[j];
#pragma unroll
            for (int i = 0; i < 32; i++) v += l_f1[p][i] * l_fw1[i * 31 + j];
            td_tab[p * 32 + j] = fmaxf(v, 0.f);
        } else {
            td_tab[p * 32 + 31] = 0.f;
        }
    }

    // ---- bf16 weight transposes (independent of td path)
    for (int idx = tid; idx < 2048; idx += 256) {   // W0T[j*32+i] = gw0[i][j]
        const int j = idx >> 5, i = idx & 31;
        w0t[idx] = f2bf(gw0[i * 64 + j]);
    }
    for (int idx = tid; idx < 8192; idx += 256) {   // W1T[e*64+j] = gw1[j][e]
        const int e = idx >> 6, j = idx & 63;
        w1t[idx] = f2bf(gw1[j * 128 + e]);
    }
}

// ---------------------------------------------------------------------------
// Main: one wave per block, APW atoms per wave. Per atom:
// geometry -> st(bf16,LDS) -> L1 MFMA(+bias,relu,+st residual) -> h1(bf16,LDS)
//   + B[j][d] = sum_k h1[k][j] * rt[k][d]            (G residual, pushed down)
// L2 MFMA -> relu part folded directly into A[e][d] (+= B[e&63])
// D[e][m] = sum_d A[e][d]*A[m][d], coalesced float4 stores.
// ---------------------------------------------------------------------------
__global__ __launch_bounds__(64, 2) void descr_mfma(
    const float* __restrict__ inputs, const int* __restrict__ input_types,
    const int* __restrict__ neigh_list, const float* __restrict__ length,
    const float* __restrict__ gb0, const float* __restrict__ gb1,
    const float* __restrict__ td_tab, const unsigned short* __restrict__ w0t,
    const unsigned short* __restrict__ w1t, float* __restrict__ out)
{
    __shared__ __align__(16) unsigned short s_st[64 * ST_ST];  // 5 KB
    __shared__ __align__(16) unsigned short s_h1[64 * ST_H1];  // 9 KB
    __shared__ __align__(16) float s_rt[64 * 4];               // 1 KB
    __shared__ __align__(16) float s_A[128 * 4];               // 2 KB
    __shared__ __align__(16) float s_B[64 * 4];                // 1 KB

    const int lane = threadIdx.x;
    const int l15 = lane & 15;
    const int q = lane >> 4;

    // Weight fragments, resident in registers for the whole wave lifetime.
    // B-frag layout (16x16x32): lane holds B[k = q*8 + jj][n = l15 (+16*tile)]
    bf16x8 w0f[4];
#pragma unroll
    for (int nt = 0; nt < 4; nt++)
        w0f[nt] = *(const bf16x8*)&w0t[(nt * 16 + l15) * 32 + q * 8];
    bf16x8 w1f[8][2];
#pragma unroll
    for (int et = 0; et < 8; et++) {
        w1f[et][0] = *(const bf16x8*)&w1t[(et * 16 + l15) * 64 + q * 8];
        w1f[et][1] = *(const bf16x8*)&w1t[(et * 16 + l15) * 64 + 32 + q * 8];
    }
    float b0f[4], b1f[8];
#pragma unroll
    for (int jt = 0; jt < 4; jt++) b0f[jt] = gb0[jt * 16 + l15];
#pragma unroll
    for (int et = 0; et < 8; et++) b1f[et] = gb1[et * 16 + l15];
    const float Lx = length[0], Ly = length[1], Lz = length[2];

    for (int aa = 0; aa < APW; aa++) {
        const int atom = blockIdx.x * APW + aa;
        const int sidx = atom >> 11;

        // ---- geometry: lane = neighbor k
        {
            const int nb = neigh_list[atom * K_DIM + lane];
            const bool msk = nb < 0;
            const int idx = msk ? 0 : nb;
            const float cx = inputs[atom * 3 + 0];
            const float cy = inputs[atom * 3 + 1];
            const float cz = inputs[atom * 3 + 2];
            const int nbase = (sidx * N_DIM + idx) * 3;
            float dx = inputs[nbase + 0] - cx;
            float dy = inputs[nbase + 1] - cy;
            float dz = inputs[nbase + 2] - cz;
            dx -= Lx * rintf(dx / Lx);
            dy -= Ly * rintf(dy / Ly);
            dz -= Lz * rintf(dz / Lz);
            const float rsq = dx * dx + dy * dy + dz * dz;
            const float r = sqrtf(rsq > 0.f ? rsq : 1.f);
            const float inv = 1.f / r;
            float sw;
            if (r < 6.f) sw = inv;
            else if (r < 12.f) {
                const float u = (r - 6.f) * (1.f / 6.f);
                sw = inv * (0.5f * __cosf(3.14159265358979323846f * u) + 0.5f);
            } else sw = 0.f;
            const bool valid = (!msk) && (rsq > 0.f);
            const float sij = valid ? sw : 0.f;
            const float f = sij * inv;
            *(float4*)&s_rt[lane * 4] = make_float4(sij, dx * f, dy * f, dz * f);

            const int ct = input_types[atom];
            const int ntp = input_types[sidx * N_DIM + idx];
            const float* tdr = &td_tab[(ct * 2 + ntp) * 32];
            const float zm = msk ? 0.f : 1.f;
            unsigned* strow = (unsigned*)&s_st[lane * ST_ST];
#pragma unroll
            for (int i = 0; i < 16; i++) {
                const float a = tdr[2 * i] * zm;
                const float b = (i == 15) ? sij : tdr[2 * i + 1] * zm;
                strow[i] = (unsigned)f2bf(a) | ((unsigned)f2bf(b) << 16);
            }
        }
        __syncthreads();

        // ---- L1 (M=k64, N=j64, K=i32) + B-term accumulation
        f32x4 Bp[4] = {{0.f,0.f,0.f,0.f},{0.f,0.f,0.f,0.f},{0.f,0.f,0.f,0.f},{0.f,0.f,0.f,0.f}};
#pragma unroll
        for (int mt = 0; mt < 4; mt++) {
            const bf16x8 afr = *(const bf16x8*)&s_st[(mt * 16 + l15) * ST_ST + q * 8];
            f32x4 c1[4];
#pragma unroll
            for (int jt = 0; jt < 4; jt++) {
                f32x4 z = {0.f, 0.f, 0.f, 0.f};
                c1[jt] = __builtin_amdgcn_mfma_f32_16x16x32_bf16(afr, w0f[jt], z, 0, 0, 0);
            }
            f32x4 rtr[4];
#pragma unroll
            for (int reg = 0; reg < 4; reg++)
                rtr[reg] = *(const f32x4*)&s_rt[(mt * 16 + q * 4 + reg) * 4];
#pragma unroll
            for (int jt = 0; jt < 4; jt++) {
                const int jcol = (jt & 1) * 16 + l15;
#pragma unroll
                for (int reg = 0; reg < 4; reg++) {
                    const int k = mt * 16 + q * 4 + reg;
                    const float h = fmaxf(c1[jt][reg] + b0f[jt], 0.f) + bf2f(s_st[k * ST_ST + jcol]);
                    Bp[jt] += h * rtr[reg];
                    s_h1[k * ST_H1 + jt * 16 + l15] = f2bf(h);
                }
            }
        }
#pragma unroll
        for (int jt = 0; jt < 4; jt++) Bp[jt] = quad_reduce(Bp[jt]);
        if (lane < 16) {
#pragma unroll
            for (int jt = 0; jt < 4; jt++)
                *(f32x4*)&s_B[(jt * 16 + lane) * 4] = Bp[jt];
        }
        __syncthreads();

        // ---- L2 (M=k64, N=e128, K=j64) + A accumulation (relu part only)
        f32x4 Ap[8] = {{0.f,0.f,0.f,0.f},{0.f,0.f,0.f,0.f},{0.f,0.f,0.f,0.f},{0.f,0.f,0.f,0.f},
                       {0.f,0.f,0.f,0.f},{0.f,0.f,0.f,0.f},{0.f,0.f,0.f,0.f},{0.f,0.f,0.f,0.f}};
#pragma unroll
        for (int kt = 0; kt < 4; kt++) {
            const bf16x8 a0 = *(const bf16x8*)&s_h1[(kt * 16 + l15) * ST_H1 + q * 8];
            const bf16x8 a1 = *(const bf16x8*)&s_h1[(kt * 16 + l15) * ST_H1 + 32 + q * 8];
            f32x4 rtr[4];
#pragma unroll
            for (int reg = 0; reg < 4; reg++)
                rtr[reg] = *(const f32x4*)&s_rt[(kt * 16 + q * 4 + reg) * 4];
#pragma unroll
            for (int et = 0; et < 8; et++) {
                f32x4 c2 = {0.f, 0.f, 0.f, 0.f};
                c2 = __builtin_amdgcn_mfma_f32_16x16x32_bf16(a0, w1f[et][0], c2, 0, 0, 0);
                c2 = __builtin_amdgcn_mfma_f32_16x16x32_bf16(a1, w1f[et][1], c2, 0, 0, 0);
#pragma unroll
                for (int reg = 0; reg < 4; reg++) {
                    const float g = fmaxf(c2[reg] + b1f[et], 0.f);
                    Ap[et] += g * rtr[reg];
                }
            }
        }
#pragma unroll
        for (int et = 0; et < 8; et++) Ap[et] = quad_reduce(Ap[et]);
        if (lane < 16) {
#pragma unroll
            for (int et = 0; et < 8; et++) {
                const int e = et * 16 + lane;
                const f32x4 bb = *(const f32x4*)&s_B[(e & 63) * 4];
                const f32x4 v = Ap[et] + bb;
                *(f32x4*)&s_A[e * 4] = v;
            }
        }
        __syncthreads();

        // ---- D[e][m] = dot(A[e], A[m]), m<16; coalesced float4 stores
        {
            const int m0 = (lane & 3) * 4;
            const int er = lane >> 2;
            f32x4 Am[4];
#pragma unroll
            for (int t = 0; t < 4; t++) Am[t] = *(const f32x4*)&s_A[(m0 + t) * 4];
            float* op = out + (size_t)atom * 2048;
#pragma unroll
            for (int g = 0; g < 8; g++) {
                const int e = g * 16 + er;
                const f32x4 Ae = *(const f32x4*)&s_A[e * 4];
                f32x4 o;
                o[0] = Ae[0]*Am[0][0] + Ae[1]*Am[0][1] + Ae[2]*Am[0][2] + Ae[3]*Am[0][3];
                o[1] = Ae[0]*Am[1][0] + Ae[1]*Am[1][1] + Ae[2]*Am[1][2] + Ae[3]*Am[1][3];
                o[2] = Ae[0]*Am[2][0] + Ae[1]*Am[2][1] + Ae[2]*Am[2][2] + Ae[3]*Am[2][3];
                o[3] = Ae[0]*Am[3][0] + Ae[1]*Am[3][1] + Ae[2]*Am[3][2] + Ae[3]*Am[3][3];
                *(f32x4*)&op[e * 16 + m0] = o;
            }
        }
        __syncthreads();
    }
}

extern "C" void kernel_launch(void* const* d_in, const int* in_sizes, int n_in,
                              void* d_out, int out_size, void* d_ws, size_t ws_size,
                              hipStream_t stream) {
    (void)in_sizes; (void)n_in; (void)out_size; (void)ws_size;
    const float* inputs      = (const float*)d_in[0];
    const int*   input_types = (const int*)d_in[1];
    const int*   neigh_list  = (const int*)d_in[2];
    const float* length      = (const float*)d_in[3];
    const float* ew0 = (const float*)d_in[4];
    const float* eb0 = (const float*)d_in[5];
    const float* ew1 = (const float*)d_in[6];
    const float* eb1 = (const float*)d_in[7];
    const float* fw0 = (const float*)d_in[8];
    const float* fb0 = (const float*)d_in[9];
    const float* fw1 = (const float*)d_in[10];
    const float* fb1 = (const float*)d_in[11];
    const float* gw0 = (const float*)d_in[12];
    const float* gb0 = (const float*)d_in[13];
    const float* gw1 = (const float*)d_in[14];
    const float* gb1 = (const float*)d_in[15];
    float* out = (float*)d_out;

    float* td_tab = (float*)d_ws;                                      // 128 f32
    unsigned short* w0t = (unsigned short*)((char*)d_ws + 512);        // 2048 bf16
    unsigned short* w1t = (unsigned short*)((char*)d_ws + 512 + 4096); // 8192 bf16

    hipLaunchKernelGGL(prep_kernel, dim3(1), dim3(256), 0, stream,
                       ew0, eb0, ew1, eb1, fw0, fb0, fw1, fb1, gw0, gw1,
                       td_tab, w0t, w1t);

    const int nblocks = (S_DIM * N_DIM) / APW;   // 4096
    hipLaunchKernelGGL(descr_mfma, dim3(nblocks), dim3(64), 0, stream,
                       inputs, input_types, neigh_list, length,
                       gb0, gb1, td_tab, w0t, w1t, out);
}

// Round 4
// 229.276 us; speedup vs baseline: 4.2572x; 1.0695x over previous
//
#include <hip/hip_runtime.h>
#include <math.h>

#define S_DIM 8
#define N_DIM 2048
#define K_DIM 64
#define APW 4          // atoms per wave (= per 64-thread block)
#define ST_ST 40       // s_tilde row stride, bf16 units (80 B rows, 16B-aligned)
#define ST_H1 72       // h1 row stride, bf16 units (144 B rows, 16B-aligned)

typedef __attribute__((ext_vector_type(8))) short bf16x8;
typedef __attribute__((ext_vector_type(4))) float f32x4;
typedef __attribute__((ext_vector_type(4))) int   i32x4;

__device__ __forceinline__ unsigned asu(float x) {
    union { float f; unsigned u; } v; v.f = x; return v.u;
}
__device__ __forceinline__ unsigned short f2bf(float x) {
    unsigned u = asu(x);
    return (unsigned short)((u + 0x7FFFu + ((u >> 16) & 1u)) >> 16);
}
__device__ __forceinline__ float bf2f(unsigned short h) {
    union { unsigned u; float f; } v; v.u = ((unsigned)h) << 16; return v.f;
}
// round-nearest-even packed pair (x -> lo16, y -> hi16)
__device__ __forceinline__ unsigned rne_pk(float x, float y) {
    unsigned ux = asu(x), uy = asu(y);
    return ((ux + 0x7FFFu + ((ux >> 16) & 1u)) >> 16) |
           ((uy + 0x7FFFu + ((uy >> 16) & 1u)) & 0xFFFF0000u);
}
// truncation packed pair (cheap; used only for MFMA operand packs)
__device__ __forceinline__ unsigned trn_pk(float x, float y) {
    return (asu(x) >> 16) | (asu(y) & 0xFFFF0000u);
}
// K=16-in-K=32 fragment: 4 real bf16 (2 packed dwords) + 4 zeros
__device__ __forceinline__ bf16x8 half_frag(unsigned p0, unsigned p1) {
    union { i32x4 i; bf16x8 b; } u;
    u.i = (i32x4){(int)p0, (int)p1, 0, 0};
    return u.b;
}

// ---------------------------------------------------------------------------
// Prep: packed td table (4 pairs x 16 u32 of bf16-pairs) + bf16 weights.
// Weights staged to LDS coalesced, MLP parallelized (R2 lesson: 4-thread
// global-chase version was 103 us).
// ---------------------------------------------------------------------------
__global__ __launch_bounds__(256) void prep_kernel(
        const float* __restrict__ ew0, const float* __restrict__ eb0,
        const float* __restrict__ ew1, const float* __restrict__ eb1,
        const float* __restrict__ fw0, const float* __restrict__ fb0,
        const float* __restrict__ fw1, const float* __restrict__ fb1,
        const float* __restrict__ gw0, const float* __restrict__ gw1,
        unsigned* __restrict__ td_pk,
        unsigned short* __restrict__ w0t, unsigned short* __restrict__ w1t) {
    __shared__ float l_ew0[32], l_eb0[16], l_ew1[512], l_eb1[32];
    __shared__ float l_fw0[1024], l_fb0[32], l_fw1[992], l_fb1[31];
    __shared__ float l_h[4][2][16];
    __shared__ float l_tv[4][32];
    __shared__ float l_f1[4][32];
    __shared__ float l_td[4][32];

    const int tid = threadIdx.x;
    if (tid < 32) l_ew0[tid] = ew0[tid];
    if (tid < 16) l_eb0[tid] = eb0[tid];
    for (int i = tid; i < 512; i += 256) l_ew1[i] = ew1[i];
    if (tid < 32) l_eb1[tid] = eb1[tid];
    for (int i = tid; i < 1024; i += 256) l_fw0[i] = fw0[i];
    if (tid < 32) l_fb0[tid] = fb0[tid];
    for (int i = tid; i < 992; i += 256) l_fw1[i] = fw1[i];
    if (tid < 31) l_fb1[tid] = fb1[tid];
    __syncthreads();

    if (tid < 128) {
        const int p = tid >> 5, ord = (tid >> 4) & 1, j = tid & 15;
        const float c = (float)(p >> 1), t = (float)(p & 1);
        const float x0 = ord ? t : c;
        const float x1 = ord ? c : t;
        l_h[p][ord][j] = fmaxf(x0 * l_ew0[j] + x1 * l_ew0[16 + j] + l_eb0[j], 0.f);
    }
    __syncthreads();
    if (tid < 128) {
        const int p = tid >> 5, j = tid & 31;
        float acc = 0.f;
#pragma unroll
        for (int ord = 0; ord < 2; ord++) {
            float v = l_eb1[j];
#pragma unroll
            for (int i = 0; i < 16; i++) v += l_h[p][ord][i] * l_ew1[i * 32 + j];
            acc += fmaxf(v, 0.f);
        }
        l_tv[p][j] = acc;
    }
    __syncthreads();
    if (tid < 128) {
        const int p = tid >> 5, j = tid & 31;
        float v = l_fb0[j];
#pragma unroll
        for (int i = 0; i < 32; i++) v += l_tv[p][i] * l_fw0[i * 32 + j];
        l_f1[p][j] = fmaxf(v, 0.f);
    }
    __syncthreads();
    if (tid < 128) {
        const int p = tid >> 5, j = tid & 31;
        if (j < 31) {
            float v = l_fb1[j];
#pragma unroll
            for (int i = 0; i < 32; i++) v += l_f1[p][i] * l_fw1[i * 31 + j];
            l_td[p][j] = fmaxf(v, 0.f);
        } else {
            l_td[p][31] = 0.f;
        }
    }
    __syncthreads();
    if (tid < 64) {   // pack: td_pk[p*16+i] = bf(td[2i]) | bf(td[2i+1])<<16
        const int p = tid >> 4, i = tid & 15;
        const unsigned lo = f2bf(l_td[p][2 * i]);
        const unsigned hi = (i == 15) ? 0u : (unsigned)f2bf(l_td[p][2 * i + 1]);
        td_pk[tid] = lo | (hi << 16);
    }

    for (int idx = tid; idx < 2048; idx += 256) {   // W0T[j*32+i] = gw0[i][j]
        const int j = idx >> 5, i = idx & 31;
        w0t[idx] = f2bf(gw0[i * 64 + j]);
    }
    for (int idx = tid; idx < 8192; idx += 256) {   // W1T[e*64+j] = gw1[j][e]
        const int e = idx >> 6, j = idx & 63;
        w1t[idx] = f2bf(gw1[j * 128 + e]);
    }
}

// ---------------------------------------------------------------------------
// Main: one wave per block. Per atom:
// geometry -> st(bf16,LDS via packed td) , rt^T (f32, LDS)
// L1 MFMA -> h1 (epilogue in regs) -> s_h1 + BjT += rtT x h1   (MFMA, K16-pad)
// L2 MFMA -> g (regs) -> AT += rtT x g                         (MFMA, K16-pad)
// A = AT + BjT[e&63] -> s_A (q=0 lanes) -> D = A A16^T -> out
// ---------------------------------------------------------------------------
__global__ __launch_bounds__(64, 2) void descr_mfma(
    const float* __restrict__ inputs, const int* __restrict__ input_types,
    const int* __restrict__ neigh_list, const float* __restrict__ length,
    const float* __restrict__ gb0, const float* __restrict__ gb1,
    const unsigned* __restrict__ td_pk, const unsigned short* __restrict__ w0t,
    const unsigned short* __restrict__ w1t, float* __restrict__ out)
{
    __shared__ __align__(16) unsigned short s_st[64 * ST_ST];  // 5.1 KB; overlaid by s_A after L1
    __shared__ __align__(16) unsigned short s_h1[64 * ST_H1];  // 9.2 KB
    __shared__ __align__(16) float s_rtT[4 * 68];              // 1.1 KB, rt^T rows d=0..3
    __shared__ unsigned s_tdpk[64];
    float* s_A = (float*)s_st;                                 // 2 KB overlay (st dead after L1)

    const int lane = threadIdx.x;
    const int l15 = lane & 15;
    const int q = lane >> 4;

    // static weight fragments (B-layout, verified in R3)
    bf16x8 w0f[4];
#pragma unroll
    for (int nt = 0; nt < 4; nt++)
        w0f[nt] = *(const bf16x8*)&w0t[(nt * 16 + l15) * 32 + q * 8];
    bf16x8 w1f[8][2];
#pragma unroll
    for (int et = 0; et < 8; et++) {
        w1f[et][0] = *(const bf16x8*)&w1t[(et * 16 + l15) * 64 + q * 8];
        w1f[et][1] = *(const bf16x8*)&w1t[(et * 16 + l15) * 64 + 32 + q * 8];
    }
    float b0f[4], b1f[8];
#pragma unroll
    for (int jt = 0; jt < 4; jt++) b0f[jt] = gb0[jt * 16 + l15];
#pragma unroll
    for (int et = 0; et < 8; et++) b1f[et] = gb1[et * 16 + l15];
    s_tdpk[lane] = td_pk[lane];
    const float Lx = length[0], Ly = length[1], Lz = length[2];
    const float iLx = 1.f / Lx, iLy = 1.f / Ly, iLz = 1.f / Lz;

    const f32x4 zf = {0.f, 0.f, 0.f, 0.f};

    for (int aa = 0; aa < APW; aa++) {
        const int atom = blockIdx.x * APW + aa;
        const int sidx = atom >> 11;

        __syncthreads();   // protects s_st/s_rtT overwrite vs previous iter reads

        // ---- geometry: lane = neighbor k
        {
            const int nb = neigh_list[atom * K_DIM + lane];
            const bool msk = nb < 0;
            const int idx = msk ? 0 : nb;
            const float cx = inputs[atom * 3 + 0];
            const float cy = inputs[atom * 3 + 1];
            const float cz = inputs[atom * 3 + 2];
            const int nbase = (sidx * N_DIM + idx) * 3;
            float dx = inputs[nbase + 0] - cx;
            float dy = inputs[nbase + 1] - cy;
            float dz = inputs[nbase + 2] - cz;
            dx -= Lx * rintf(dx * iLx);
            dy -= Ly * rintf(dy * iLy);
            dz -= Lz * rintf(dz * iLz);
            const float rsq = dx * dx + dy * dy + dz * dz;
            const float r = sqrtf(rsq > 0.f ? rsq : 1.f);
            const float inv = 1.f / r;
            float sw;
            if (r < 6.f) sw = inv;
            else if (r < 12.f) {
                const float u = (r - 6.f) * (1.f / 6.f);
                sw = inv * (0.5f * __cosf(3.14159265358979323846f * u) + 0.5f);
            } else sw = 0.f;
            const bool valid = (!msk) && (rsq > 0.f);
            const float sij = valid ? sw : 0.f;
            const float f = sij * inv;
            s_rtT[0 * 68 + lane] = sij;
            s_rtT[1 * 68 + lane] = dx * f;
            s_rtT[2 * 68 + lane] = dy * f;
            s_rtT[3 * 68 + lane] = dz * f;

            const int ct = input_types[atom];
            const int ntp = input_types[sidx * N_DIM + idx];
            const unsigned* tdr = &s_tdpk[(ct * 2 + ntp) * 16];
            const unsigned zmask = msk ? 0u : 0xFFFFFFFFu;
            unsigned* strow = (unsigned*)&s_st[lane * ST_ST];
#pragma unroll
            for (int i = 0; i < 15; i++) strow[i] = tdr[i] & zmask;
            strow[15] = (tdr[15] & zmask & 0xFFFFu) | (((unsigned)f2bf(sij)) << 16);
            // zero pad region so b128 frag reads see clean data
            strow[16] = 0; strow[17] = 0; strow[18] = 0; strow[19] = 0;
        }
        __syncthreads();

        // ---- rt^T fragments (A-operand of Bj/A steps), K16-padded, RNE
        bf16x8 rtf[4];
#pragma unroll
        for (int a = 0; a < 4; a++) {
            const f32x4 rv = *(const f32x4*)&s_rtT[(l15 & 3) * 68 + a * 16 + q * 4];
            rtf[a] = half_frag(rne_pk(rv[0], rv[1]), rne_pk(rv[2], rv[3]));
        }

        // ---- L1 (M=k64, N=j64, K=i32) + Bj MFMA accumulation
        f32x4 Bj[4] = {zf, zf, zf, zf};
#pragma unroll
        for (int mt = 0; mt < 4; mt++) {
            const bf16x8 afr = *(const bf16x8*)&s_st[(mt * 16 + l15) * ST_ST + q * 8];
            f32x4 c1[4];
#pragma unroll
            for (int jt = 0; jt < 4; jt++)
                c1[jt] = __builtin_amdgcn_mfma_f32_16x16x32_bf16(afr, w0f[jt], zf, 0, 0, 0);
#pragma unroll
            for (int jt = 0; jt < 4; jt++) {
                float hv[4];
#pragma unroll
                for (int reg = 0; reg < 4; reg++) {
                    const int k = mt * 16 + q * 4 + reg;
                    const float r = bf2f(s_st[k * ST_ST + (jt & 1) * 16 + l15]);
                    hv[reg] = fmaxf(c1[jt][reg] + b0f[jt], 0.f) + r;
                    s_h1[k * ST_H1 + jt * 16 + l15] = f2bf(hv[reg]);
                }
                const bf16x8 hf = half_frag(trn_pk(hv[0], hv[1]), trn_pk(hv[2], hv[3]));
                Bj[jt] = __builtin_amdgcn_mfma_f32_16x16x32_bf16(rtf[mt], hf, Bj[jt], 0, 0, 0);
            }
        }
        __syncthreads();

        // ---- L2 (M=k64, N=e128, K=j64) + A MFMA accumulation
        f32x4 AT[8] = {zf, zf, zf, zf, zf, zf, zf, zf};
#pragma unroll
        for (int kt = 0; kt < 4; kt++) {
            const bf16x8 a0 = *(const bf16x8*)&s_h1[(kt * 16 + l15) * ST_H1 + q * 8];
            const bf16x8 a1 = *(const bf16x8*)&s_h1[(kt * 16 + l15) * ST_H1 + 32 + q * 8];
#pragma unroll
            for (int et = 0; et < 8; et++) {
                f32x4 c2 = __builtin_amdgcn_mfma_f32_16x16x32_bf16(a0, w1f[et][0], zf, 0, 0, 0);
                c2 = __builtin_amdgcn_mfma_f32_16x16x32_bf16(a1, w1f[et][1], c2, 0, 0, 0);
                const float g0 = fmaxf(c2[0] + b1f[et], 0.f);
                const float g1 = fmaxf(c2[1] + b1f[et], 0.f);
                const float g2 = fmaxf(c2[2] + b1f[et], 0.f);
                const float g3 = fmaxf(c2[3] + b1f[et], 0.f);
                const bf16x8 gf = half_frag(trn_pk(g0, g1), trn_pk(g2, g3));
                AT[et] = __builtin_amdgcn_mfma_f32_16x16x32_bf16(rtf[kt], gf, AT[et], 0, 0, 0);
            }
        }

        // ---- A = AT + BjT[e&63]; valid rows d=0..3 live in q==0 lanes
        if (lane < 16) {
#pragma unroll
            for (int et = 0; et < 8; et++) {
                const f32x4 v = AT[et] + Bj[et & 3];
                *(f32x4*)&s_A[(et * 16 + lane) * 4] = v;
            }
        }
        __syncthreads();

        // ---- D[e][m] = dot(A[e], A[m]), m<16; coalesced float4 stores
        {
            const int m0 = (lane & 3) * 4;
            const int er = lane >> 2;
            f32x4 Am[4];
#pragma unroll
            for (int t = 0; t < 4; t++) Am[t] = *(const f32x4*)&s_A[(m0 + t) * 4];
            float* op = out + (size_t)atom * 2048;
#pragma unroll
            for (int g = 0; g < 8; g++) {
                const int e = g * 16 + er;
                const f32x4 Ae = *(const f32x4*)&s_A[e * 4];
                f32x4 o;
                o[0] = Ae[0]*Am[0][0] + Ae[1]*Am[0][1] + Ae[2]*Am[0][2] + Ae[3]*Am[0][3];
                o[1] = Ae[0]*Am[1][0] + Ae[1]*Am[1][1] + Ae[2]*Am[1][2] + Ae[3]*Am[1][3];
                o[2] = Ae[0]*Am[2][0] + Ae[1]*Am[2][1] + Ae[2]*Am[2][2] + Ae[3]*Am[2][3];
                o[3] = Ae[0]*Am[3][0] + Ae[1]*Am[3][1] + Ae[2]*Am[3][2] + Ae[3]*Am[3][3];
                *(f32x4*)&op[e * 16 + m0] = o;
            }
        }
    }
}

extern "C" void kernel_launch(void* const* d_in, const int* in_sizes, int n_in,
                              void* d_out, int out_size, void* d_ws, size_t ws_size,
                              hipStream_t stream) {
    (void)in_sizes; (void)n_in; (void)out_size; (void)ws_size;
    const float* inputs      = (const float*)d_in[0];
    const int*   input_types = (const int*)d_in[1];
    const int*   neigh_list  = (const int*)d_in[2];
    const float* length      = (const float*)d_in[3];
    const float* ew0 = (const float*)d_in[4];
    const float* eb0 = (const float*)d_in[5];
    const float* ew1 = (const float*)d_in[6];
    const float* eb1 = (const float*)d_in[7];
    const float* fw0 = (const float*)d_in[8];
    const float* fb0 = (const float*)d_in[9];
    const float* fw1 = (const float*)d_in[10];
    const float* fb1 = (const float*)d_in[11];
    const float* gw0 = (const float*)d_in[12];
    const float* gb0 = (const float*)d_in[13];
    const float* gw1 = (const float*)d_in[14];
    const float* gb1 = (const float*)d_in[15];
    float* out = (float*)d_out;

    unsigned* td_pk = (unsigned*)d_ws;                                 // 64 u32
    unsigned short* w0t = (unsigned short*)((char*)d_ws + 512);        // 2048 bf16
    unsigned short* w1t = (unsigned short*)((char*)d_ws + 512 + 4096); // 8192 bf16

    hipLaunchKernelGGL(prep_kernel, dim3(1), dim3(256), 0, stream,
                       ew0, eb0, ew1, eb1, fw0, fb0, fw1, fb1, gw0, gw1,
                       td_pk, w0t, w1t);

    const int nblocks = (S_DIM * N_DIM) / APW;   // 4096
    hipLaunchKernelGGL(descr_mfma, dim3(nblocks), dim3(64), 0, stream,
                       inputs, input_types, neigh_list, length,
                       gb0, gb1, td_pk, w0t, w1t, out);
}